// Round 3
// baseline (4020.649 us; speedup 1.0000x reference)
//
#include <hip/hip_runtime.h>
#include <type_traits>

// LSTM_69879117906487: T=256,B=256,I=1024,H=256,FC=128,C=8
// Round 3: eliminate per-step W_hh L2 streaming (the round-2 bottleneck).
//   k_zero      : zero the per-(group,step) sync counters (every launch!)
//   k_bias      : bias = b_ih + b_hh
//   k_xg_mfma   : xg = x @ W_ih^T + bias, fp16 MFMA, 128x128 tile (unchanged)
//   k_lstm_sync : 64 blocks = 16 batch-groups x 4 j-slices. W-slice (128 KB)
//                 lives in REGISTERS (64 VGPR/thread). Per-step cross-block
//                 h exchange through h_all + release/acquire counters.
//   k_fc        : relu -> FC1(relu) -> FC2 (unchanged, reads fp16 h_all)

typedef float    f4    __attribute__((ext_vector_type(4)));
typedef float    f32x4 __attribute__((ext_vector_type(4)));
typedef _Float16 h8    __attribute__((ext_vector_type(8)));

__device__ __forceinline__ float ldf(const float* p)    { return *p; }
__device__ __forceinline__ float ldf(const _Float16* p) { return (float)*p; }

__device__ __forceinline__ float fast_sigmoid(float x) {
    return 1.f / (1.f + __expf(-x));
}
__device__ __forceinline__ float fast_tanh(float x) {
    const float e = __expf(-2.f * fabsf(x));
    const float t = (1.f - e) / (1.f + e);
    return copysignf(t, x);
}

// ---------------------------------------------------------------- zero sync counters
__global__ __launch_bounds__(256) void k_zero(unsigned int* __restrict__ cnt) {
    cnt[blockIdx.x * 256 + threadIdx.x] = 0u;   // 16 groups x 256 steps
}

// ---------------------------------------------------------------- bias
__global__ __launch_bounds__(256) void k_bias(const float* __restrict__ b_ih,
                                              const float* __restrict__ b_hh,
                                              float* __restrict__ bias) {
    const int i = blockIdx.x * 256 + threadIdx.x;
    if (i < 1024) bias[i] = b_ih[i] + b_hh[i];
}

// ---------------------------------------------------------------- xg GEMM (MFMA)
__global__ __launch_bounds__(256) void k_xg_mfma(
    const float* __restrict__ x, const float* __restrict__ W_ih,
    const float* __restrict__ bias, _Float16* __restrict__ xg)
{
    __shared__ _Float16 As[2][128][40];
    __shared__ _Float16 Bs[2][128][40];
    const int tid = threadIdx.x;
    const int l   = tid & 63;
    const int w   = tid >> 6;
    const int m0  = blockIdx.y * 128;
    const int n0  = blockIdx.x * 128;
    const int wr  = (w >> 1) * 64;
    const int wc  = (w & 1) * 64;
    const int srow = tid >> 2;
    const int skof = (tid & 3) * 8;
    const int lr = l & 15;
    const int lk = (l >> 4) * 8;

    f32x4 acc[4][4] = {};
    f4 ldA[2][2], ldB[2][2];

    auto XG_LOAD = [&](int kt) {
        const int k0 = kt * 32;
        #pragma unroll
        for (int s = 0; s < 2; ++s) {
            const float* xa = &x[(size_t)(m0 + srow + s * 64) * 1024 + k0 + skof];
            const float* wb = &W_ih[(size_t)(n0 + srow + s * 64) * 1024 + k0 + skof];
            ldA[s][0] = *(const f4*)xa; ldA[s][1] = *(const f4*)(xa + 4);
            ldB[s][0] = *(const f4*)wb; ldB[s][1] = *(const f4*)(wb + 4);
        }
    };
    auto XG_WRITE = [&](int buf) {
        #pragma unroll
        for (int s = 0; s < 2; ++s) {
            h8 va, vb;
            #pragma unroll
            for (int c = 0; c < 8; ++c) {
                va[c] = (_Float16)ldA[s][c >> 2][c & 3];
                vb[c] = (_Float16)ldB[s][c >> 2][c & 3];
            }
            *(h8*)&As[buf][srow + s * 64][skof] = va;
            *(h8*)&Bs[buf][srow + s * 64][skof] = vb;
        }
    };

    XG_LOAD(0);
    XG_WRITE(0);
    __syncthreads();
    for (int kt = 0; kt < 32; ++kt) {
        const int cur = kt & 1;
        if (kt + 1 < 32) XG_LOAD(kt + 1);
        h8 af[4], bf[4];
        #pragma unroll
        for (int mf = 0; mf < 4; ++mf) af[mf] = *(const h8*)&As[cur][wr + mf * 16 + lr][lk];
        #pragma unroll
        for (int nf = 0; nf < 4; ++nf) bf[nf] = *(const h8*)&Bs[cur][wc + nf * 16 + lr][lk];
        #pragma unroll
        for (int mf = 0; mf < 4; ++mf)
            #pragma unroll
            for (int nf = 0; nf < 4; ++nf)
                acc[mf][nf] = __builtin_amdgcn_mfma_f32_16x16x32_f16(af[mf], bf[nf], acc[mf][nf], 0, 0, 0);
        if (kt + 1 < 32) XG_WRITE((kt + 1) & 1);
        __syncthreads();
    }
    #pragma unroll
    for (int nf = 0; nf < 4; ++nf) {
        const int col = n0 + wc + nf * 16 + lr;
        const float bv = bias[col];
        #pragma unroll
        for (int mf = 0; mf < 4; ++mf) {
            #pragma unroll
            for (int r = 0; r < 4; ++r) {
                const int row = m0 + wr + mf * 16 + (l >> 4) * 4 + r;
                xg[(size_t)row * 1024 + col] = (_Float16)(acc[mf][nf][r] + bv);
            }
        }
    }
}

// ---------------------------------------------------------------- recurrence (W-in-register, 4-block groups)
// blockIdx.x = s*16 + g  (g = batch group 0..15, s = j-slice 0..3).
// Group members {g, g+16, g+32, g+48} are all == g (mod 8)  -> same XCD.
// Block owns j in [s*64, s*64+64): W-slice rows {gate*256 + s*64 + j} = 256
// rows of W_hh, held as 16 MFMA B-fragments/thread (64 VGPR).
// Per step: MFMA z-slice -> z_lds -> gates (c in regs) -> h-slice to h_all
// -> fence -> counter release; next step acquires partners' counter.
__global__ __launch_bounds__(512, 2) void k_lstm_sync(
    const _Float16* __restrict__ xg, const float* __restrict__ W_hh,
    _Float16* __restrict__ h_all, unsigned int* __restrict__ cnt)
{
    __shared__ float z_lds[16 * 264];   // rows=batch(16), stride 264 f32
    const int tid = threadIdx.x;
    const int w   = tid >> 6;
    const int l   = tid & 63;
    const int lr  = l & 15;
    const int lk  = (l >> 4) * 8;
    const int g   = blockIdx.x & 15;
    const int s   = blockIdx.x >> 4;
    const int b0  = g * 16;
    unsigned int* my_cnt = cnt + g * 256;

    // ---- load W-slice into registers (one-time): 2 col-tiles x 8 k-blocks
    // tile ct = u*8 + w: gate = ct>>2, j-tile = ct&3.
    // B-frag lane l elem e: W_hh[gate*256 + s*64 + (ct&3)*16 + (l&15)][kb*32 + lk + e]
    h8 Wf[2][8];
    #pragma unroll
    for (int u = 0; u < 2; ++u) {
        const int ct   = u * 8 + w;
        const int grow = (ct >> 2) * 256 + s * 64 + (ct & 3) * 16 + lr;
        #pragma unroll
        for (int kb = 0; kb < 8; ++kb) {
            const float* src = &W_hh[(size_t)grow * 256 + kb * 32 + lk];
            const f4 v0 = *(const f4*)src;
            const f4 v1 = *(const f4*)(src + 4);
            h8 hv;
            #pragma unroll
            for (int c = 0; c < 4; ++c) { hv[c] = (_Float16)v0[c]; hv[c + 4] = (_Float16)v1[c]; }
            Wf[u][kb] = hv;
        }
    }

    // ---- phase-2 identity: idx = u*512+tid -> batch row pb[u] = u*8+w, j = l
    const int pb0 = w, pb1 = 8 + w;
    const int pj  = l;
    float c_reg[2] = {0.f, 0.f};

    // prefetch xg[0] at phase-2 positions
    float xq[2][4];
    #pragma unroll
    for (int u = 0; u < 2; ++u) {
        const int pb = u ? pb1 : pb0;
        #pragma unroll
        for (int gate = 0; gate < 4; ++gate)
            xq[u][gate] = (float)xg[(size_t)(b0 + pb) * 1024 + gate * 256 + s * 64 + pj];
    }

    for (int t = 0; t < 256; ++t) {
        // issue next step's xg loads early (latency hidden under this step)
        float xqn[2][4];
        if (t < 255) {
            #pragma unroll
            for (int u = 0; u < 2; ++u) {
                const int pb = u ? pb1 : pb0;
                #pragma unroll
                for (int gate = 0; gate < 4; ++gate)
                    xqn[u][gate] = (float)xg[(size_t)((t + 1) * 256 + b0 + pb) * 1024 + gate * 256 + s * 64 + pj];
            }
        }

        f32x4 acc0 = {0.f, 0.f, 0.f, 0.f};
        f32x4 acc1 = {0.f, 0.f, 0.f, 0.f};
        if (t > 0) {
            // wait for all 4 blocks of the group to have published h[t-1]
            if (tid == 0) {
                while (__hip_atomic_load(&my_cnt[t - 1], __ATOMIC_ACQUIRE,
                                         __HIP_MEMORY_SCOPE_AGENT) < 4u) { }
            }
            __syncthreads();
            // A-fragments: h[t-1], 16 batch rows x full k=256
            const _Float16* hrow = h_all + ((size_t)(t - 1) * 256 + b0 + lr) * 256 + lk;
            h8 a[8];
            #pragma unroll
            for (int kb = 0; kb < 8; ++kb) a[kb] = *(const h8*)(hrow + kb * 32);
            #pragma unroll
            for (int kb = 0; kb < 8; ++kb) {
                acc0 = __builtin_amdgcn_mfma_f32_16x16x32_f16(a[kb], Wf[0][kb], acc0, 0, 0, 0);
                acc1 = __builtin_amdgcn_mfma_f32_16x16x32_f16(a[kb], Wf[1][kb], acc1, 0, 0, 0);
            }
        }
        // write z-slice to LDS: row=(l>>4)*4+r, col = ct*16 + lr (= gate*64 + j)
        #pragma unroll
        for (int r = 0; r < 4; ++r) {
            const int zr = (l >> 4) * 4 + r;
            z_lds[zr * 264 + (0 * 8 + w) * 16 + lr] = acc0[r];
            z_lds[zr * 264 + (1 * 8 + w) * 16 + lr] = acc1[r];
        }
        __syncthreads();   // z ready

        // phase-2: gates -> c -> h for 2 (b,j) pairs per thread
        _Float16 hv16[2];
        #pragma unroll
        for (int u = 0; u < 2; ++u) {
            const int pb = u ? pb1 : pb0;
            const float zi = z_lds[pb * 264 +   0 + pj] + xq[u][0];
            const float zf = z_lds[pb * 264 +  64 + pj] + xq[u][1];
            const float zg = z_lds[pb * 264 + 128 + pj] + xq[u][2];
            const float zo = z_lds[pb * 264 + 192 + pj] + xq[u][3];
            const float ig = fast_sigmoid(zi);
            const float fg = fast_sigmoid(zf);
            const float gg = fast_tanh(zg);
            const float og = fast_sigmoid(zo);
            c_reg[u] = fg * c_reg[u] + ig * gg;
            hv16[u] = (_Float16)(og * fast_tanh(c_reg[u]));
        }
        // publish h-slice (coalesced u16 per thread)
        h_all[((size_t)t * 256 + b0 + pb0) * 256 + s * 64 + pj] = hv16[0];
        h_all[((size_t)t * 256 + b0 + pb1) * 256 + s * 64 + pj] = hv16[1];
        __threadfence();     // make h stores visible at agent scope
        __syncthreads();     // all threads stored+fenced; z_lds reads done
        if (tid == 0)
            __hip_atomic_fetch_add(&my_cnt[t], 1u, __ATOMIC_RELEASE,
                                   __HIP_MEMORY_SCOPE_AGENT);

        // rotate xg prefetch
        #pragma unroll
        for (int u = 0; u < 2; ++u)
            #pragma unroll
            for (int gate = 0; gate < 4; ++gate)
                xq[u][gate] = xqn[u][gate];
    }
}

// ---------------------------------------------------------------- FC1+FC2
template <typename HT>
__global__ __launch_bounds__(256) void k_fc(
    const HT* __restrict__ h_all, const float* __restrict__ W1,
    const float* __restrict__ b1, const float* __restrict__ W2,
    const float* __restrict__ b2, float* __restrict__ out)
{
    __shared__ __align__(16) float smem[12288];
    float* hsT = smem;
    float* w1T = smem + 4096;
    const int tid = threadIdx.x;
    const int m0 = blockIdx.x * 64;
    const int tx = tid & 15;
    const int ty = tid >> 4;
    const int r0 = ty * 4;
    const int fA = tx * 4;
    const int fB = 64 + tx * 4;
    float acc[4][8] = {};
    for (int kc = 0; kc < 4; ++kc) {
        const int k0 = kc * 64;
        __syncthreads();
        #pragma unroll
        for (int i = 0; i < 4; ++i) {
            const int fid = tid + i * 256;
            const int rr = fid >> 4;
            const int qq = fid & 15;
            const HT* p = &h_all[(size_t)(m0 + rr) * 256 + k0 + qq * 4];
            f4 v;
            if constexpr (std::is_same<HT, float>::value) {
                v = *(const f4*)p;
            } else {
                v[0] = ldf(p); v[1] = ldf(p + 1); v[2] = ldf(p + 2); v[3] = ldf(p + 3);
            }
            #pragma unroll
            for (int c = 0; c < 4; ++c)
                hsT[(qq * 4 + c) * 64 + rr] = fmaxf(v[c], 0.f);
        }
        #pragma unroll
        for (int i = 0; i < 8; ++i) {
            const int fid = tid + i * 256;
            const int ff = fid >> 4;
            const int qq = fid & 15;
            const f4 v = *(const f4*)&W1[(size_t)ff * 256 + k0 + qq * 4];
            #pragma unroll
            for (int c = 0; c < 4; ++c)
                w1T[(qq * 4 + c) * 128 + ff] = v[c];
        }
        __syncthreads();
        #pragma unroll 4
        for (int kk = 0; kk < 64; ++kk) {
            const f4 aa = *(const f4*)&hsT[kk * 64 + r0];
            const f4 ba = *(const f4*)&w1T[kk * 128 + fA];
            const f4 bb = *(const f4*)&w1T[kk * 128 + fB];
            #pragma unroll
            for (int i = 0; i < 4; ++i) {
                #pragma unroll
                for (int j = 0; j < 4; ++j) {
                    acc[i][j]     = fmaf(aa[i], ba[j], acc[i][j]);
                    acc[i][j + 4] = fmaf(aa[i], bb[j], acc[i][j + 4]);
                }
            }
        }
    }
    __syncthreads();
    float* fc1s = smem;
    #pragma unroll
    for (int j = 0; j < 4; ++j) {
        const float bbA = b1[fA + j];
        const float bbB = b1[fB + j];
        #pragma unroll
        for (int i = 0; i < 4; ++i) {
            fc1s[(r0 + i) * 132 + fA + j] = fmaxf(acc[i][j] + bbA, 0.f);
            fc1s[(r0 + i) * 132 + fB + j] = fmaxf(acc[i][j + 4] + bbB, 0.f);
        }
    }
    __syncthreads();
    const int r  = tid >> 2;
    const int c0 = (tid & 3) * 2;
    float o0 = b2[c0], o1 = b2[c0 + 1];
    #pragma unroll
    for (int fq = 0; fq < 32; ++fq) {
        const f4 p  = *(const f4*)&fc1s[r * 132 + fq * 4];
        const f4 wa = *(const f4*)&W2[(size_t)c0 * 128 + fq * 4];
        const f4 wb = *(const f4*)&W2[(size_t)(c0 + 1) * 128 + fq * 4];
        o0 += p[0] * wa[0] + p[1] * wa[1] + p[2] * wa[2] + p[3] * wa[3];
        o1 += p[0] * wb[0] + p[1] * wb[1] + p[2] * wb[2] + p[3] * wb[3];
    }
    out[(size_t)(m0 + r) * 8 + c0]     = o0;
    out[(size_t)(m0 + r) * 8 + c0 + 1] = o1;
}

// ---------------------------------------------------------------- launch
extern "C" void kernel_launch(void* const* d_in, const int* in_sizes, int n_in,
                              void* d_out, int out_size, void* d_ws, size_t ws_size,
                              hipStream_t stream)
{
    const float* x    = (const float*)d_in[0];
    const float* W_ih = (const float*)d_in[1];
    const float* W_hh = (const float*)d_in[2];
    const float* b_ih = (const float*)d_in[3];
    const float* b_hh = (const float*)d_in[4];
    const float* W1   = (const float*)d_in[5];
    const float* b1   = (const float*)d_in[6];
    const float* W2   = (const float*)d_in[7];
    const float* b2   = (const float*)d_in[8];
    float* out = (float*)d_out;
    char* ws = (char*)d_ws;

    // workspace layout (~167.8 MB)
    _Float16*     xg    = (_Float16*)ws;                       // 134,217,728 B
    _Float16*     h_all = (_Float16*)(ws + 134217728);         //  33,554,432 B
    float*        bias  = (float*)   (ws + 167772160);         //       4,096 B
    unsigned int* cnt   = (unsigned int*)(ws + 167776256);     //      16,384 B

    k_zero<<<16, 256, 0, stream>>>(cnt);                        // must run every call
    k_bias<<<4, 256, 0, stream>>>(b_ih, b_hh, bias);
    k_xg_mfma<<<dim3(8, 512), 256, 0, stream>>>(x, W_ih, bias, xg);
    k_lstm_sync<<<64, 512, 0, stream>>>(xg, W_hh, h_all, cnt);
    k_fc<_Float16><<<1024, 256, 0, stream>>>(h_all, W1, b1, W2, b2, out);
}

// Round 4
// 2216.504 us; speedup vs baseline: 1.8140x; 1.8140x over previous
//
#include <hip/hip_runtime.h>
#include <type_traits>

// LSTM_69879117906487: T=256,B=256,I=1024,H=256,FC=128,C=8
// Round 4: recurrence with W_hh resident in registers(84/128 frags/wave) +
// LDS(34) + small L2 stream(10). Single block per batch-group (NO cross-block
// sync — round-3's inter-block handshake was the regression).
//   k_bias     : bias = b_ih + b_hh
//   k_pack     : W_hh -> MFMA B-fragment-packed fp16 (512 KB)
//   k_xg_mfma  : xg2 = x @ W_ih^T + bias, fp16 MFMA, epilogue writes the
//                LSTM-lane-packed layout (128 B per (t,g,w,lane))
//   k_lstm_reg : 16 blocks x 256 thr (4 waves, 1 wave/SIMD, ~500 VGPR).
//   k_fc       : relu -> FC1(relu) -> FC2 (unchanged, reads fp16 h_all)

typedef float    f4    __attribute__((ext_vector_type(4)));
typedef float    f32x4 __attribute__((ext_vector_type(4)));
typedef _Float16 h8    __attribute__((ext_vector_type(8)));
typedef _Float16 h4    __attribute__((ext_vector_type(4)));

__device__ __forceinline__ float ldf(const float* p)    { return *p; }
__device__ __forceinline__ float ldf(const _Float16* p) { return (float)*p; }

__device__ __forceinline__ float fast_sigmoid(float x) {
    return 1.f / (1.f + __expf(-x));
}
__device__ __forceinline__ float fast_tanh(float x) {
    const float e = __expf(-2.f * fabsf(x));
    const float t = (1.f - e) / (1.f + e);
    return copysignf(t, x);
}

// ---------------------------------------------------------------- bias
__global__ __launch_bounds__(256) void k_bias(const float* __restrict__ b_ih,
                                              const float* __restrict__ b_hh,
                                              float* __restrict__ bias) {
    const int i = blockIdx.x * 256 + threadIdx.x;
    if (i < 1024) bias[i] = b_ih[i] + b_hh[i];
}

// ---------------------------------------------------------------- W_hh pack
// fi = gt*8 + kb. Lane l elem j: W_hh[gt*16 + (l&15)][kb*32 + (l>>4)*8 + j].
__global__ __launch_bounds__(256) void k_pack(const float* __restrict__ W_hh,
                                              _Float16* __restrict__ Wp) {
    const int idx = blockIdx.x * 256 + threadIdx.x;   // fi*64 + l, 32768 total
    const int fi = idx >> 6;
    const int l  = idx & 63;
    const int g  = (fi >> 3) * 16 + (l & 15);
    const int k  = (fi & 7) * 32 + ((l >> 4) << 3);
    const float* src = &W_hh[(size_t)g * 256 + k];
    h8 v;
    #pragma unroll
    for (int c = 0; c < 8; ++c) v[c] = (_Float16)src[c];
    *(h8*)&Wp[(size_t)idx * 8] = v;
}

// ---------------------------------------------------------------- xg GEMM (MFMA)
// 128x128 tile, BK=32, 256 thr. Epilogue -> xg2 packed for k_lstm_reg:
// element base E(t,g,w,l) = (((t*16+g)*4+w)*64+l)*64; value v = gate*16+jt*4+r.
__global__ __launch_bounds__(256) void k_xg_mfma(
    const float* __restrict__ x, const float* __restrict__ W_ih,
    const float* __restrict__ bias, _Float16* __restrict__ xg2)
{
    __shared__ _Float16 As[2][128][40];
    __shared__ _Float16 Bs[2][128][40];
    const int tid = threadIdx.x;
    const int l   = tid & 63;
    const int w   = tid >> 6;
    const int m0  = blockIdx.y * 128;
    const int n0  = blockIdx.x * 128;
    const int wr  = (w >> 1) * 64;
    const int wc  = (w & 1) * 64;
    const int srow = tid >> 2;
    const int skof = (tid & 3) * 8;
    const int lr = l & 15;
    const int lg = l >> 4;

    f32x4 acc[4][4] = {};
    f4 ldA[2][2], ldB[2][2];

    auto XG_LOAD = [&](int kt) {
        const int k0 = kt * 32;
        #pragma unroll
        for (int s = 0; s < 2; ++s) {
            const float* xa = &x[(size_t)(m0 + srow + s * 64) * 1024 + k0 + skof];
            const float* wb = &W_ih[(size_t)(n0 + srow + s * 64) * 1024 + k0 + skof];
            ldA[s][0] = *(const f4*)xa; ldA[s][1] = *(const f4*)(xa + 4);
            ldB[s][0] = *(const f4*)wb; ldB[s][1] = *(const f4*)(wb + 4);
        }
    };
    auto XG_WRITE = [&](int buf) {
        #pragma unroll
        for (int s = 0; s < 2; ++s) {
            h8 va, vb;
            #pragma unroll
            for (int c = 0; c < 8; ++c) {
                va[c] = (_Float16)ldA[s][c >> 2][c & 3];
                vb[c] = (_Float16)ldB[s][c >> 2][c & 3];
            }
            *(h8*)&As[buf][srow + s * 64][skof] = va;
            *(h8*)&Bs[buf][srow + s * 64][skof] = vb;
        }
    };

    XG_LOAD(0);
    XG_WRITE(0);
    __syncthreads();
    for (int kt = 0; kt < 32; ++kt) {
        const int cur = kt & 1;
        if (kt + 1 < 32) XG_LOAD(kt + 1);
        h8 af[4], bf[4];
        #pragma unroll
        for (int mf = 0; mf < 4; ++mf) af[mf] = *(const h8*)&As[cur][wr + mf * 16 + lr][lg * 8];
        #pragma unroll
        for (int nf = 0; nf < 4; ++nf) bf[nf] = *(const h8*)&Bs[cur][wc + nf * 16 + lr][lg * 8];
        #pragma unroll
        for (int mf = 0; mf < 4; ++mf)
            #pragma unroll
            for (int nf = 0; nf < 4; ++nf)
                acc[mf][nf] = __builtin_amdgcn_mfma_f32_16x16x32_f16(af[mf], bf[nf], acc[mf][nf], 0, 0, 0);
        if (kt + 1 < 32) XG_WRITE((kt + 1) & 1);
        __syncthreads();
    }
    // epilogue: C row = m0+wr+mf*16+lg*4+r, col = n0+wc+nf*16+lr.
    // Target lane in xg2 packet == this lane (derivation: (b&15)>>2 == l>>4,
    // j&15 == l&15). Each (mf,nf) -> one 8-byte store of 4 fp16 (r=0..3).
    #pragma unroll
    for (int nf = 0; nf < 4; ++nf) {
        const int col  = n0 + wc + nf * 16 + lr;
        const float bv = bias[col];
        const int gate = col >> 8;
        const int njp  = col & 255;
        const int wt   = njp >> 6;
        const int jt   = (njp >> 4) & 3;
        #pragma unroll
        for (int mf = 0; mf < 4; ++mf) {
            const int rowb = m0 + wr + mf * 16 + lg * 4;
            const int tt = rowb >> 8;
            const int gb = (rowb >> 4) & 15;
            h4 pk;
            #pragma unroll
            for (int r = 0; r < 4; ++r) pk[r] = (_Float16)(acc[mf][nf][r] + bv);
            *(h4*)&xg2[((((size_t)tt * 16 + gb) * 4 + wt) * 64 + l) * 64 + gate * 16 + jt * 4] = pk;
        }
    }
}

// ---------------------------------------------------------------- recurrence
// 16 blocks x 256 thr (4 waves, 1/SIMD, up to 512 unified VGPR+AGPR).
// Wave w owns j in [w*64,(w+1)*64): 16 tiles ti=gate*4+jt, 8 kb each.
// Frag f = ti*8+kb; global frag gt(ti)*8+kb, gt = gate*16 + w*4 + jt.
// Sources: kb<=4 all ti -> REG(80); kb==5 ti<4 -> REG(4);
//          kb==5 ti>=4 -> LDS(12); kb==6 ti<14 -> LDS(14); kb==7 ti<8 -> LDS(8);
//          kb==6 ti>=14 -> STREAM(2); kb==7 ti>=8 -> STREAM(8).
__global__ __launch_bounds__(256, 1) void k_lstm_reg(
    const _Float16* __restrict__ xg2, const _Float16* __restrict__ Wp,
    _Float16* __restrict__ h_all)
{
    __shared__ _Float16 wlds[4 * 34 * 512];   // 139,264 B
    __shared__ _Float16 h_sh[2][16][264];     //  16,896 B  (total 156,160)
    const int tid = threadIdx.x;
    const int w  = tid >> 6;
    const int l  = tid & 63;
    const int lr = l & 15;
    const int lg = l >> 4;
    const int g  = blockIdx.x;
    const int b0 = g * 16;

    auto fgid = [&](int ti, int kb) {                  // global frag index
        return (((ti >> 2) * 16 + w * 4 + (ti & 3)) * 8 + kb);
    };

    // ---- prologue: 84 register frags
    h8 Wreg[84];
    #pragma unroll
    for (int kb = 0; kb < 5; ++kb)
        #pragma unroll
        for (int ti = 0; ti < 16; ++ti)
            Wreg[kb * 16 + ti] = *(const h8*)&Wp[((size_t)fgid(ti, kb) * 64 + l) * 8];
    #pragma unroll
    for (int ti = 0; ti < 4; ++ti)
        Wreg[80 + ti] = *(const h8*)&Wp[((size_t)fgid(ti, 5) * 64 + l) * 8];

    // ---- 34 LDS frags (per wave): lidx: kb5/ti>=4 -> ti-4; kb6/ti<14 -> 12+ti; kb7/ti<8 -> 26+ti
    #pragma unroll
    for (int ti = 4; ti < 16; ++ti) {
        const h8 v = *(const h8*)&Wp[((size_t)fgid(ti, 5) * 64 + l) * 8];
        *(h8*)&wlds[((w * 34 + (ti - 4)) * 64 + l) * 8] = v;
    }
    #pragma unroll
    for (int ti = 0; ti < 14; ++ti) {
        const h8 v = *(const h8*)&Wp[((size_t)fgid(ti, 6) * 64 + l) * 8];
        *(h8*)&wlds[((w * 34 + (12 + ti)) * 64 + l) * 8] = v;
    }
    #pragma unroll
    for (int ti = 0; ti < 8; ++ti) {
        const h8 v = *(const h8*)&Wp[((size_t)fgid(ti, 7) * 64 + l) * 8];
        *(h8*)&wlds[((w * 34 + (26 + ti)) * 64 + l) * 8] = v;
    }

    // zero h_sh
    {
        _Float16* p = &h_sh[0][0][0];
        for (int i = tid; i < 2 * 16 * 264; i += 256) p[i] = (_Float16)0.f;
    }
    __syncthreads();

    float c[16];
    #pragma unroll
    for (int i = 0; i < 16; ++i) c[i] = 0.f;

    for (int t = 0; t < 256; ++t) {
        const int cur = t & 1;
        const int nxt = cur ^ 1;

        // xg packet: 128 B coalesced per lane (added post-MFMA)
        const size_t E = ((((size_t)t * 16 + g) * 4 + w) * 64 + l) * 64;
        h8 xqv[8];
        #pragma unroll
        for (int q = 0; q < 8; ++q) xqv[q] = *(const h8*)&xg2[E + q * 8];

        // streamed frags: re-read each step from L2 (anti-hoist via soff)
        unsigned soff = 0;
        asm volatile("" : "+v"(soff));
        h8 sv[10];
        #pragma unroll
        for (int s2 = 0; s2 < 8; ++s2)
            sv[s2] = *(const h8*)&Wp[((size_t)fgid(8 + s2, 7) * 64 + l) * 8 + soff];
        sv[8] = *(const h8*)&Wp[((size_t)fgid(14, 6) * 64 + l) * 8 + soff];
        sv[9] = *(const h8*)&Wp[((size_t)fgid(15, 6) * 64 + l) * 8 + soff];

        f32x4 acc[16] = {};

        // A-frag double slot, prefetch distance 1 pass
        h8 ab[2];
        ab[0] = *(const h8*)&h_sh[cur][lr][0 * 32 + lg * 8];
        ab[1] = *(const h8*)&h_sh[cur][lr][1 * 32 + lg * 8];

        #pragma unroll
        for (int kb = 0; kb < 8; ++kb) {
            const h8 av = ab[kb & 1];
            #pragma unroll
            for (int ti = 0; ti < 16; ++ti) {
                h8 b;
                if (kb <= 4)                  b = Wreg[kb * 16 + ti];
                else if (kb == 5 && ti < 4)   b = Wreg[80 + ti];
                else if (kb == 5)             b = *(const h8*)&wlds[((w * 34 + (ti - 4)) * 64 + l) * 8];
                else if (kb == 6 && ti < 14)  b = *(const h8*)&wlds[((w * 34 + (12 + ti)) * 64 + l) * 8];
                else if (kb == 6)             b = sv[8 + (ti - 14)];
                else if (ti < 8)              b = *(const h8*)&wlds[((w * 34 + (26 + ti)) * 64 + l) * 8];
                else                          b = sv[ti - 8];
                acc[ti] = __builtin_amdgcn_mfma_f32_16x16x32_f16(av, b, acc[ti], 0, 0, 0);
            }
            if (kb + 2 < 8)
                ab[kb & 1] = *(const h8*)&h_sh[cur][lr][(kb + 2) * 32 + lg * 8];
        }

        // activations: lane holds z for b = lg*4+r, j = w*64+jt*16+lr, all 4 gates
        #pragma unroll
        for (int jt = 0; jt < 4; ++jt) {
            #pragma unroll
            for (int r = 0; r < 4; ++r) {
                const int v0 = 0 * 16 + jt * 4 + r;
                const int v1 = 1 * 16 + jt * 4 + r;
                const int v2 = 2 * 16 + jt * 4 + r;
                const int v3 = 3 * 16 + jt * 4 + r;
                const float zi = acc[0 * 4 + jt][r] + (float)xqv[v0 >> 3][v0 & 7];
                const float zf = acc[1 * 4 + jt][r] + (float)xqv[v1 >> 3][v1 & 7];
                const float zg = acc[2 * 4 + jt][r] + (float)xqv[v2 >> 3][v2 & 7];
                const float zo = acc[3 * 4 + jt][r] + (float)xqv[v3 >> 3][v3 & 7];
                const float ig = fast_sigmoid(zi);
                const float fg = fast_sigmoid(zf);
                const float gg = fast_tanh(zg);
                const float og = fast_sigmoid(zo);
                const int ci = jt * 4 + r;
                c[ci] = fg * c[ci] + ig * gg;
                const float hv = og * fast_tanh(c[ci]);
                const _Float16 h16 = (_Float16)hv;
                h_sh[nxt][lg * 4 + r][w * 64 + jt * 16 + lr] = h16;
                h_all[((size_t)t * 256 + b0 + lg * 4 + r) * 256 + w * 64 + jt * 16 + lr] = h16;
            }
        }
        __syncthreads();
    }
}

// ---------------------------------------------------------------- FC1+FC2
template <typename HT>
__global__ __launch_bounds__(256) void k_fc(
    const HT* __restrict__ h_all, const float* __restrict__ W1,
    const float* __restrict__ b1, const float* __restrict__ W2,
    const float* __restrict__ b2, float* __restrict__ out)
{
    __shared__ __align__(16) float smem[12288];
    float* hsT = smem;
    float* w1T = smem + 4096;
    const int tid = threadIdx.x;
    const int m0 = blockIdx.x * 64;
    const int tx = tid & 15;
    const int ty = tid >> 4;
    const int r0 = ty * 4;
    const int fA = tx * 4;
    const int fB = 64 + tx * 4;
    float acc[4][8] = {};
    for (int kc = 0; kc < 4; ++kc) {
        const int k0 = kc * 64;
        __syncthreads();
        #pragma unroll
        for (int i = 0; i < 4; ++i) {
            const int fid = tid + i * 256;
            const int rr = fid >> 4;
            const int qq = fid & 15;
            const HT* p = &h_all[(size_t)(m0 + rr) * 256 + k0 + qq * 4];
            f4 v;
            if constexpr (std::is_same<HT, float>::value) {
                v = *(const f4*)p;
            } else {
                v[0] = ldf(p); v[1] = ldf(p + 1); v[2] = ldf(p + 2); v[3] = ldf(p + 3);
            }
            #pragma unroll
            for (int cc = 0; cc < 4; ++cc)
                hsT[(qq * 4 + cc) * 64 + rr] = fmaxf(v[cc], 0.f);
        }
        #pragma unroll
        for (int i = 0; i < 8; ++i) {
            const int fid = tid + i * 256;
            const int ff = fid >> 4;
            const int qq = fid & 15;
            const f4 v = *(const f4*)&W1[(size_t)ff * 256 + k0 + qq * 4];
            #pragma unroll
            for (int cc = 0; cc < 4; ++cc)
                w1T[(qq * 4 + cc) * 128 + ff] = v[cc];
        }
        __syncthreads();
        #pragma unroll 4
        for (int kk = 0; kk < 64; ++kk) {
            const f4 aa = *(const f4*)&hsT[kk * 64 + r0];
            const f4 ba = *(const f4*)&w1T[kk * 128 + fA];
            const f4 bb = *(const f4*)&w1T[kk * 128 + fB];
            #pragma unroll
            for (int i = 0; i < 4; ++i) {
                #pragma unroll
                for (int j = 0; j < 4; ++j) {
                    acc[i][j]     = fmaf(aa[i], ba[j], acc[i][j]);
                    acc[i][j + 4] = fmaf(aa[i], bb[j], acc[i][j + 4]);
                }
            }
        }
    }
    __syncthreads();
    float* fc1s = smem;
    #pragma unroll
    for (int j = 0; j < 4; ++j) {
        const float bbA = b1[fA + j];
        const float bbB = b1[fB + j];
        #pragma unroll
        for (int i = 0; i < 4; ++i) {
            fc1s[(r0 + i) * 132 + fA + j] = fmaxf(acc[i][j] + bbA, 0.f);
            fc1s[(r0 + i) * 132 + fB + j] = fmaxf(acc[i][j + 4] + bbB, 0.f);
        }
    }
    __syncthreads();
    const int r  = tid >> 2;
    const int c0 = (tid & 3) * 2;
    float o0 = b2[c0], o1 = b2[c0 + 1];
    #pragma unroll
    for (int fq = 0; fq < 32; ++fq) {
        const f4 p  = *(const f4*)&fc1s[r * 132 + fq * 4];
        const f4 wa = *(const f4*)&W2[(size_t)c0 * 128 + fq * 4];
        const f4 wb = *(const f4*)&W2[(size_t)(c0 + 1) * 128 + fq * 4];
        o0 += p[0] * wa[0] + p[1] * wa[1] + p[2] * wa[2] + p[3] * wa[3];
        o1 += p[0] * wb[0] + p[1] * wb[1] + p[2] * wb[2] + p[3] * wb[3];
    }
    out[(size_t)(m0 + r) * 8 + c0]     = o0;
    out[(size_t)(m0 + r) * 8 + c0 + 1] = o1;
}

// ---------------------------------------------------------------- launch
extern "C" void kernel_launch(void* const* d_in, const int* in_sizes, int n_in,
                              void* d_out, int out_size, void* d_ws, size_t ws_size,
                              hipStream_t stream)
{
    const float* x    = (const float*)d_in[0];
    const float* W_ih = (const float*)d_in[1];
    const float* W_hh = (const float*)d_in[2];
    const float* b_ih = (const float*)d_in[3];
    const float* b_hh = (const float*)d_in[4];
    const float* W1   = (const float*)d_in[5];
    const float* b1   = (const float*)d_in[6];
    const float* W2   = (const float*)d_in[7];
    const float* b2   = (const float*)d_in[8];
    float* out = (float*)d_out;
    char* ws = (char*)d_ws;

    // workspace layout (168,300,544 B — identical footprint to round 2)
    _Float16* xg2   = (_Float16*)ws;                          // 134,217,728 B
    _Float16* h_all = (_Float16*)(ws + 134217728);            //  33,554,432 B
    _Float16* Wp    = (_Float16*)(ws + 167772160);            //     524,288 B
    float*    bias  = (float*)   (ws + 168296448);            //       4,096 B

    k_bias<<<4, 256, 0, stream>>>(b_ih, b_hh, bias);
    k_pack<<<128, 256, 0, stream>>>(W_hh, Wp);
    k_xg_mfma<<<dim3(8, 512), 256, 0, stream>>>(x, W_ih, bias, xg2);
    k_lstm_reg<<<16, 256, 0, stream>>>(xg2, Wp, h_all);
    k_fc<_Float16><<<1024, 256, 0, stream>>>(h_all, W1, b1, W2, b2, out);
}

// Round 6
// 2086.400 us; speedup vs baseline: 1.9271x; 1.0624x over previous
//
#include <hip/hip_runtime.h>
#include <type_traits>

// LSTM_69879117906487: T=256,B=256,I=1024,H=256,FC=128,C=8
// Round 6: W_hh residency, fixed. Per wave (128 B-frags of 4 regs each):
//   63 frags in AGPRs  (plain init; "a"-constrained MFMA B-operand forces
//                       AGPR allocation; compiler emits v_accvgpr_write once)
//   21 frags in VGPRs
//   35 frags in LDS    (143 KB)
//    9 frags streamed  from L2 each step (36 KB/step/block, latency-hidden)
// acc is initialized from xg (MFMA C-operand accumulates) so the 32 xg regs
// die at step start -> arch-VGPR pressure ~228, no spills (R4's failure).

typedef float    f4    __attribute__((ext_vector_type(4)));
typedef float    f32x4 __attribute__((ext_vector_type(4)));
typedef _Float16 h8    __attribute__((ext_vector_type(8)));
typedef _Float16 h4    __attribute__((ext_vector_type(4)));

__device__ __forceinline__ float ldf(const float* p)    { return *p; }
__device__ __forceinline__ float ldf(const _Float16* p) { return (float)*p; }

__device__ __forceinline__ float fast_sigmoid(float x) {
    return 1.f / (1.f + __expf(-x));
}
__device__ __forceinline__ float fast_tanh(float x) {
    const float e = __expf(-2.f * fabsf(x));
    const float t = (1.f - e) / (1.f + e);
    return copysignf(t, x);
}

// MFMA with B-operand read directly from AGPRs (D/C in VGPR -- legal mix;
// R5's error was D=a with C=v, i.e. D/C file mismatch).
__device__ __forceinline__ void mfma_agpr(f32x4& acc, h8 a, const f32x4& b) {
    asm("v_mfma_f32_16x16x32_f16 %0, %1, %2, %0"
        : "+v"(acc) : "v"(a), "a"(b));
}

// ---------------------------------------------------------------- bias
__global__ __launch_bounds__(256) void k_bias(const float* __restrict__ b_ih,
                                              const float* __restrict__ b_hh,
                                              float* __restrict__ bias) {
    const int i = blockIdx.x * 256 + threadIdx.x;
    if (i < 1024) bias[i] = b_ih[i] + b_hh[i];
}

// ---------------------------------------------------------------- W_hh pack
// fi = gt*8 + kb. Lane l elem j: W_hh[gt*16 + (l&15)][kb*32 + (l>>4)*8 + j].
__global__ __launch_bounds__(256) void k_pack(const float* __restrict__ W_hh,
                                              _Float16* __restrict__ Wp) {
    const int idx = blockIdx.x * 256 + threadIdx.x;
    const int fi = idx >> 6;
    const int l  = idx & 63;
    const int g  = (fi >> 3) * 16 + (l & 15);
    const int k  = (fi & 7) * 32 + ((l >> 4) << 3);
    const float* src = &W_hh[(size_t)g * 256 + k];
    h8 v;
    #pragma unroll
    for (int c = 0; c < 8; ++c) v[c] = (_Float16)src[c];
    *(h8*)&Wp[(size_t)idx * 8] = v;
}

// ---------------------------------------------------------------- xg GEMM (MFMA)
__global__ __launch_bounds__(256) void k_xg_mfma(
    const float* __restrict__ x, const float* __restrict__ W_ih,
    const float* __restrict__ bias, _Float16* __restrict__ xg2)
{
    __shared__ _Float16 As[2][128][40];
    __shared__ _Float16 Bs[2][128][40];
    const int tid = threadIdx.x;
    const int l   = tid & 63;
    const int w   = tid >> 6;
    const int m0  = blockIdx.y * 128;
    const int n0  = blockIdx.x * 128;
    const int wr  = (w >> 1) * 64;
    const int wc  = (w & 1) * 64;
    const int srow = tid >> 2;
    const int skof = (tid & 3) * 8;
    const int lr = l & 15;
    const int lg = l >> 4;

    f32x4 acc[4][4] = {};
    f4 ldA[2][2], ldB[2][2];

    auto XG_LOAD = [&](int kt) {
        const int k0 = kt * 32;
        #pragma unroll
        for (int s = 0; s < 2; ++s) {
            const float* xa = &x[(size_t)(m0 + srow + s * 64) * 1024 + k0 + skof];
            const float* wb = &W_ih[(size_t)(n0 + srow + s * 64) * 1024 + k0 + skof];
            ldA[s][0] = *(const f4*)xa; ldA[s][1] = *(const f4*)(xa + 4);
            ldB[s][0] = *(const f4*)wb; ldB[s][1] = *(const f4*)(wb + 4);
        }
    };
    auto XG_WRITE = [&](int buf) {
        #pragma unroll
        for (int s = 0; s < 2; ++s) {
            h8 va, vb;
            #pragma unroll
            for (int c = 0; c < 8; ++c) {
                va[c] = (_Float16)ldA[s][c >> 2][c & 3];
                vb[c] = (_Float16)ldB[s][c >> 2][c & 3];
            }
            *(h8*)&As[buf][srow + s * 64][skof] = va;
            *(h8*)&Bs[buf][srow + s * 64][skof] = vb;
        }
    };

    XG_LOAD(0);
    XG_WRITE(0);
    __syncthreads();
    for (int kt = 0; kt < 32; ++kt) {
        const int cur = kt & 1;
        if (kt + 1 < 32) XG_LOAD(kt + 1);
        h8 af[4], bf[4];
        #pragma unroll
        for (int mf = 0; mf < 4; ++mf) af[mf] = *(const h8*)&As[cur][wr + mf * 16 + lr][lg * 8];
        #pragma unroll
        for (int nf = 0; nf < 4; ++nf) bf[nf] = *(const h8*)&Bs[cur][wc + nf * 16 + lr][lg * 8];
        #pragma unroll
        for (int mf = 0; mf < 4; ++mf)
            #pragma unroll
            for (int nf = 0; nf < 4; ++nf)
                acc[mf][nf] = __builtin_amdgcn_mfma_f32_16x16x32_f16(af[mf], bf[nf], acc[mf][nf], 0, 0, 0);
        if (kt + 1 < 32) XG_WRITE((kt + 1) & 1);
        __syncthreads();
    }
    #pragma unroll
    for (int nf = 0; nf < 4; ++nf) {
        const int col  = n0 + wc + nf * 16 + lr;
        const float bv = bias[col];
        const int gate = col >> 8;
        const int njp  = col & 255;
        const int wt   = njp >> 6;
        const int jt   = (njp >> 4) & 3;
        #pragma unroll
        for (int mf = 0; mf < 4; ++mf) {
            const int rowb = m0 + wr + mf * 16 + lg * 4;
            const int tt = rowb >> 8;
            const int gb = (rowb >> 4) & 15;
            h4 pk;
            #pragma unroll
            for (int r = 0; r < 4; ++r) pk[r] = (_Float16)(acc[mf][nf][r] + bv);
            *(h4*)&xg2[((((size_t)tt * 16 + gb) * 4 + wt) * 64 + l) * 64 + gate * 16 + jt * 4] = pk;
        }
    }
}

// ---------------------------------------------------------------- recurrence
// 16 blocks x 256 thr (4 waves, 1 wave/SIMD). Frag (ti,kb), ti=gate*4+jt:
//   AGPR 63 : kb in {0,1,2} all ti (48) + kb==3 ti<15 (15)
//   VGPR 21 : kb==3 ti==15 (1) + kb==4 all (16) + kb==7 ti<4 (4)
//   LDS  35 : kb==5 all (16) + kb==6 all (16) + kb==7 ti in {4,5,6} (3)
//   STREAM 9: kb==7 ti in [7,16)
__global__ __launch_bounds__(256, 1) void k_lstm_agpr(
    const _Float16* __restrict__ xg2, const _Float16* __restrict__ Wp,
    _Float16* __restrict__ h_all)
{
    __shared__ _Float16 wlds[4 * 35 * 512];   // 143,360 B
    __shared__ _Float16 h_sh[2][16][264];     //  16,896 B  (total 160,256)
    const int tid = threadIdx.x;
    const int w  = tid >> 6;
    const int l  = tid & 63;
    const int lr = l & 15;
    const int lg = l >> 4;
    const int g  = blockIdx.x;
    const int b0 = g * 16;

    auto fgid = [&](int ti, int kb) {
        return (((ti >> 2) * 16 + w * 4 + (ti & 3)) * 8 + kb);
    };
    auto ldfrag = [&](int ti, int kb) {
        return *(const h8*)&Wp[((size_t)fgid(ti, kb) * 64 + l) * 8];
    };

    // ---- 63 AGPR frags: only consumed through "a"-constrained asm, so the
    // allocator assigns AGPRs and emits one-time v_accvgpr_write copies here.
    f32x4 wag[63];
    #pragma unroll
    for (int kb = 0; kb < 3; ++kb)
        #pragma unroll
        for (int ti = 0; ti < 16; ++ti)
            wag[kb * 16 + ti] = __builtin_bit_cast(f32x4, ldfrag(ti, kb));
    #pragma unroll
    for (int ti = 0; ti < 15; ++ti)
        wag[48 + ti] = __builtin_bit_cast(f32x4, ldfrag(ti, 3));

    // ---- 21 VGPR frags
    h8 wvg[21];
    wvg[0] = ldfrag(15, 3);
    #pragma unroll
    for (int ti = 0; ti < 16; ++ti) wvg[1 + ti] = ldfrag(ti, 4);
    #pragma unroll
    for (int ti = 0; ti < 4; ++ti) wvg[17 + ti] = ldfrag(ti, 7);

    // ---- 35 LDS frags: kb5 -> ti, kb6 -> 16+ti, kb7 ti in {4,5,6} -> 32+(ti-4)
    #pragma unroll
    for (int ti = 0; ti < 16; ++ti)
        *(h8*)&wlds[((w * 35 + ti) * 64 + l) * 8] = ldfrag(ti, 5);
    #pragma unroll
    for (int ti = 0; ti < 16; ++ti)
        *(h8*)&wlds[((w * 35 + 16 + ti) * 64 + l) * 8] = ldfrag(ti, 6);
    #pragma unroll
    for (int ti = 4; ti < 7; ++ti)
        *(h8*)&wlds[((w * 35 + 32 + (ti - 4)) * 64 + l) * 8] = ldfrag(ti, 7);

    // zero h_sh
    {
        _Float16* p = &h_sh[0][0][0];
        for (int i = tid; i < 2 * 16 * 264; i += 256) p[i] = (_Float16)0.f;
    }
    __syncthreads();

    float c[16];
    #pragma unroll
    for (int i = 0; i < 16; ++i) c[i] = 0.f;

    for (int t = 0; t < 256; ++t) {
        const int cur = t & 1;
        const int nxt = cur ^ 1;

        // xg packet: 128 B coalesced per lane; feeds acc init, then regs die.
        const size_t E = ((((size_t)t * 16 + g) * 4 + w) * 64 + l) * 64;
        h8 xqv[8];
        #pragma unroll
        for (int q = 0; q < 8; ++q) xqv[q] = *(const h8*)&xg2[E + q * 8];

        h8 ab[2];
        ab[0] = *(const h8*)&h_sh[cur][lr][0 * 32 + lg * 8];
        ab[1] = *(const h8*)&h_sh[cur][lr][1 * 32 + lg * 8];

        // acc init = xg (MFMA C-operand accumulates the rest)
        f32x4 acc[16];
        #pragma unroll
        for (int ti = 0; ti < 16; ++ti) {
            #pragma unroll
            for (int r = 0; r < 4; ++r) {
                const int v = (ti >> 2) * 16 + (ti & 3) * 4 + r;
                acc[ti][r] = (float)xqv[v >> 3][v & 7];
            }
        }

        // 9 streamed frags (kb==7, ti 7..15); soff asm sits after acc init so
        // these loads can't be hoisted into the xqv-live window.
        unsigned soff = 0;
        asm volatile("" : "+v"(soff));
        h8 sv[9];
        #pragma unroll
        for (int s2 = 0; s2 < 9; ++s2)
            sv[s2] = *(const h8*)&Wp[((size_t)fgid(7 + s2, 7) * 64 + l) * 8 + soff];

        #pragma unroll
        for (int kb = 0; kb < 8; ++kb) {
            const h8 av = ab[kb & 1];
            #pragma unroll
            for (int ti = 0; ti < 16; ++ti) {
                if (kb < 3) {
                    mfma_agpr(acc[ti], av, wag[kb * 16 + ti]);
                } else if (kb == 3) {
                    if (ti < 15) mfma_agpr(acc[ti], av, wag[48 + ti]);
                    else acc[ti] = __builtin_amdgcn_mfma_f32_16x16x32_f16(av, wvg[0], acc[ti], 0, 0, 0);
                } else if (kb == 4) {
                    acc[ti] = __builtin_amdgcn_mfma_f32_16x16x32_f16(av, wvg[1 + ti], acc[ti], 0, 0, 0);
                } else if (kb == 5) {
                    const h8 b = *(const h8*)&wlds[((w * 35 + ti) * 64 + l) * 8];
                    acc[ti] = __builtin_amdgcn_mfma_f32_16x16x32_f16(av, b, acc[ti], 0, 0, 0);
                } else if (kb == 6) {
                    const h8 b = *(const h8*)&wlds[((w * 35 + 16 + ti) * 64 + l) * 8];
                    acc[ti] = __builtin_amdgcn_mfma_f32_16x16x32_f16(av, b, acc[ti], 0, 0, 0);
                } else {
                    h8 b;
                    if (ti < 4)      b = wvg[17 + ti];
                    else if (ti < 7) b = *(const h8*)&wlds[((w * 35 + 32 + (ti - 4)) * 64 + l) * 8];
                    else             b = sv[ti - 7];
                    acc[ti] = __builtin_amdgcn_mfma_f32_16x16x32_f16(av, b, acc[ti], 0, 0, 0);
                }
            }
            if (kb + 2 < 8)
                ab[kb & 1] = *(const h8*)&h_sh[cur][lr][(kb + 2) * 32 + lg * 8];
        }

        // activations: lane holds z for b = lg*4+r, j = w*64+jt*16+lr, all 4 gates
        #pragma unroll
        for (int jt = 0; jt < 4; ++jt) {
            #pragma unroll
            for (int r = 0; r < 4; ++r) {
                const float ig = fast_sigmoid(acc[0 * 4 + jt][r]);
                const float fg = fast_sigmoid(acc[1 * 4 + jt][r]);
                const float gg = fast_tanh(acc[2 * 4 + jt][r]);
                const float og = fast_sigmoid(acc[3 * 4 + jt][r]);
                const int ci = jt * 4 + r;
                c[ci] = fg * c[ci] + ig * gg;
                const float hv = og * fast_tanh(c[ci]);
                const _Float16 h16 = (_Float16)hv;
                h_sh[nxt][lg * 4 + r][w * 64 + jt * 16 + lr] = h16;
                h_all[((size_t)t * 256 + b0 + lg * 4 + r) * 256 + w * 64 + jt * 16 + lr] = h16;
            }
        }
        __syncthreads();
    }
}

// ---------------------------------------------------------------- FC1+FC2
template <typename HT>
__global__ __launch_bounds__(256) void k_fc(
    const HT* __restrict__ h_all, const float* __restrict__ W1,
    const float* __restrict__ b1, const float* __restrict__ W2,
    const float* __restrict__ b2, float* __restrict__ out)
{
    __shared__ __align__(16) float smem[12288];
    float* hsT = smem;
    float* w1T = smem + 4096;
    const int tid = threadIdx.x;
    const int m0 = blockIdx.x * 64;
    const int tx = tid & 15;
    const int ty = tid >> 4;
    const int r0 = ty * 4;
    const int fA = tx * 4;
    const int fB = 64 + tx * 4;
    float acc[4][8] = {};
    for (int kc = 0; kc < 4; ++kc) {
        const int k0 = kc * 64;
        __syncthreads();
        #pragma unroll
        for (int i = 0; i < 4; ++i) {
            const int fid = tid + i * 256;
            const int rr = fid >> 4;
            const int qq = fid & 15;
            const HT* p = &h_all[(size_t)(m0 + rr) * 256 + k0 + qq * 4];
            f4 v;
            if constexpr (std::is_same<HT, float>::value) {
                v = *(const f4*)p;
            } else {
                v[0] = ldf(p); v[1] = ldf(p + 1); v[2] = ldf(p + 2); v[3] = ldf(p + 3);
            }
            #pragma unroll
            for (int cc = 0; cc < 4; ++cc)
                hsT[(qq * 4 + cc) * 64 + rr] = fmaxf(v[cc], 0.f);
        }
        #pragma unroll
        for (int i = 0; i < 8; ++i) {
            const int fid = tid + i * 256;
            const int ff = fid >> 4;
            const int qq = fid & 15;
            const f4 v = *(const f4*)&W1[(size_t)ff * 256 + k0 + qq * 4];
            #pragma unroll
            for (int cc = 0; cc < 4; ++cc)
                w1T[(qq * 4 + cc) * 128 + ff] = v[cc];
        }
        __syncthreads();
        #pragma unroll 4
        for (int kk = 0; kk < 64; ++kk) {
            const f4 aa = *(const f4*)&hsT[kk * 64 + r0];
            const f4 ba = *(const f4*)&w1T[kk * 128 + fA];
            const f4 bb = *(const f4*)&w1T[kk * 128 + fB];
            #pragma unroll
            for (int i = 0; i < 4; ++i) {
                #pragma unroll
                for (int j = 0; j < 4; ++j) {
                    acc[i][j]     = fmaf(aa[i], ba[j], acc[i][j]);
                    acc[i][j + 4] = fmaf(aa[i], bb[j], acc[i][j + 4]);
                }
            }
        }
    }
    __syncthreads();
    float* fc1s = smem;
    #pragma unroll
    for (int j = 0; j < 4; ++j) {
        const float bbA = b1[fA + j];
        const float bbB = b1[fB + j];
        #pragma unroll
        for (int i = 0; i < 4; ++i) {
            fc1s[(r0 + i) * 132 + fA + j] = fmaxf(acc[i][j] + bbA, 0.f);
            fc1s[(r0 + i) * 132 + fB + j] = fmaxf(acc[i][j + 4] + bbB, 0.f);
        }
    }
    __syncthreads();
    const int r  = tid >> 2;
    const int c0 = (tid & 3) * 2;
    float o0 = b2[c0], o1 = b2[c0 + 1];
    #pragma unroll
    for (int fq = 0; fq < 32; ++fq) {
        const f4 p  = *(const f4*)&fc1s[r * 132 + fq * 4];
        const f4 wa = *(const f4*)&W2[(size_t)c0 * 128 + fq * 4];
        const f4 wb = *(const f4*)&W2[(size_t)(c0 + 1) * 128 + fq * 4];
        o0 += p[0] * wa[0] + p[1] * wa[1] + p[2] * wa[2] + p[3] * wa[3];
        o1 += p[0] * wb[0] + p[1] * wb[1] + p[2] * wb[2] + p[3] * wb[3];
    }
    out[(size_t)(m0 + r) * 8 + c0]     = o0;
    out[(size_t)(m0 + r) * 8 + c0 + 1] = o1;
}

// ---------------------------------------------------------------- launch
extern "C" void kernel_launch(void* const* d_in, const int* in_sizes, int n_in,
                              void* d_out, int out_size, void* d_ws, size_t ws_size,
                              hipStream_t stream)
{
    const float* x    = (const float*)d_in[0];
    const float* W_ih = (const float*)d_in[1];
    const float* W_hh = (const float*)d_in[2];
    const float* b_ih = (const float*)d_in[3];
    const float* b_hh = (const float*)d_in[4];
    const float* W1   = (const float*)d_in[5];
    const float* b1   = (const float*)d_in[6];
    const float* W2   = (const float*)d_in[7];
    const float* b2   = (const float*)d_in[8];
    float* out = (float*)d_out;
    char* ws = (char*)d_ws;

    // workspace layout (168,300,544 B)
    _Float16* xg2   = (_Float16*)ws;                          // 134,217,728 B
    _Float16* h_all = (_Float16*)(ws + 134217728);            //  33,554,432 B
    _Float16* Wp    = (_Float16*)(ws + 167772160);            //     524,288 B
    float*    bias  = (float*)   (ws + 168296448);            //       4,096 B

    k_bias<<<4, 256, 0, stream>>>(b_ih, b_hh, bias);
    k_pack<<<128, 256, 0, stream>>>(W_hh, Wp);
    k_xg_mfma<<<dim3(8, 512), 256, 0, stream>>>(x, W_ih, bias, xg2);
    k_lstm_agpr<<<16, 256, 0, stream>>>(xg2, Wp, h_all);
    k_fc<_Float16><<<1024, 256, 0, stream>>>(h_all, W1, b1, W2, b2, out);
}

// Round 9
// 1996.364 us; speedup vs baseline: 2.0140x; 1.0451x over previous
//
#include <hip/hip_runtime.h>
#include <type_traits>

// LSTM_69879117906487: T=256,B=256,I=1024,H=256,FC=128,C=8
// Round 9: all-builtin recurrence (asm MFMA abandoned after 2 corrupt rounds).
// Diagnosis: R2 (8 waves, full stream) = L1-fill-BW-bound ~29 B/cyc;
//            R6 (4 waves, 1/SIMD, partial residency) = LATENCY-bound 19 B/cyc.
// Fix: 8 waves (2/SIMD latency hiding) + residency (less traffic):
//   per wave (64 frags): VGPR 24 (kb0-2) + LDS 17 (kb3,4 + kb5/ti0) + stream 23.
//   Block streams 184 KB/step (vs R6 288, R2 512).
//   k_xg_mfma epilogue -> 64B/lane packets for the 8-wave consumer.

typedef float    f4    __attribute__((ext_vector_type(4)));
typedef float    f32x4 __attribute__((ext_vector_type(4)));
typedef _Float16 h8    __attribute__((ext_vector_type(8)));
typedef _Float16 h4    __attribute__((ext_vector_type(4)));

__device__ __forceinline__ float ldf(const float* p)    { return *p; }
__device__ __forceinline__ float ldf(const _Float16* p) { return (float)*p; }

__device__ __forceinline__ float fast_sigmoid(float x) {
    return 1.f / (1.f + __expf(-x));
}
__device__ __forceinline__ float fast_tanh(float x) {
    const float e = __expf(-2.f * fabsf(x));
    const float t = (1.f - e) / (1.f + e);
    return copysignf(t, x);
}

// ---------------------------------------------------------------- bias
__global__ __launch_bounds__(256) void k_bias(const float* __restrict__ b_ih,
                                              const float* __restrict__ b_hh,
                                              float* __restrict__ bias) {
    const int i = blockIdx.x * 256 + threadIdx.x;
    if (i < 1024) bias[i] = b_ih[i] + b_hh[i];
}

// ---------------------------------------------------------------- W_hh pack
// fi = gt*8 + kb (gt = 16-gate tile 0..63, kb = 32-k block 0..7).
// Lane l elem j: W_hh[gt*16 + (l&15)][kb*32 + (l>>4)*8 + j]; 16 B/lane.
__global__ __launch_bounds__(256) void k_pack(const float* __restrict__ W_hh,
                                              _Float16* __restrict__ Wp) {
    const int idx = blockIdx.x * 256 + threadIdx.x;
    const int fi = idx >> 6;
    const int l  = idx & 63;
    const int g  = (fi >> 3) * 16 + (l & 15);
    const int k  = (fi & 7) * 32 + ((l >> 4) << 3);
    const float* src = &W_hh[(size_t)g * 256 + k];
    h8 v;
    #pragma unroll
    for (int c = 0; c < 8; ++c) v[c] = (_Float16)src[c];
    *(h8*)&Wp[(size_t)idx * 8] = v;
}

// ---------------------------------------------------------------- xg GEMM (MFMA)
// 128x128 tile, BK=32, 256 thr. Epilogue -> xg2 packets for k_lstm_8w:
// packet base = (((t*16+g)*8 + w8)*64 + lane)*32, elem v = gate*8 + jt*4 + r
// where w8 = (col>>5)&7, jt = (col>>4)&1, gate = col>>8.
__global__ __launch_bounds__(256) void k_xg_mfma(
    const float* __restrict__ x, const float* __restrict__ W_ih,
    const float* __restrict__ bias, _Float16* __restrict__ xg2)
{
    __shared__ _Float16 As[2][128][40];
    __shared__ _Float16 Bs[2][128][40];
    const int tid = threadIdx.x;
    const int l   = tid & 63;
    const int w   = tid >> 6;
    const int m0  = blockIdx.y * 128;
    const int n0  = blockIdx.x * 128;
    const int wr  = (w >> 1) * 64;
    const int wc  = (w & 1) * 64;
    const int srow = tid >> 2;
    const int skof = (tid & 3) * 8;
    const int lr = l & 15;
    const int lg = l >> 4;

    f32x4 acc[4][4] = {};
    f4 ldA[2][2], ldB[2][2];

    auto XG_LOAD = [&](int kt) {
        const int k0 = kt * 32;
        #pragma unroll
        for (int s = 0; s < 2; ++s) {
            const float* xa = &x[(size_t)(m0 + srow + s * 64) * 1024 + k0 + skof];
            const float* wb = &W_ih[(size_t)(n0 + srow + s * 64) * 1024 + k0 + skof];
            ldA[s][0] = *(const f4*)xa; ldA[s][1] = *(const f4*)(xa + 4);
            ldB[s][0] = *(const f4*)wb; ldB[s][1] = *(const f4*)(wb + 4);
        }
    };
    auto XG_WRITE = [&](int buf) {
        #pragma unroll
        for (int s = 0; s < 2; ++s) {
            h8 va, vb;
            #pragma unroll
            for (int c = 0; c < 8; ++c) {
                va[c] = (_Float16)ldA[s][c >> 2][c & 3];
                vb[c] = (_Float16)ldB[s][c >> 2][c & 3];
            }
            *(h8*)&As[buf][srow + s * 64][skof] = va;
            *(h8*)&Bs[buf][srow + s * 64][skof] = vb;
        }
    };

    XG_LOAD(0);
    XG_WRITE(0);
    __syncthreads();
    for (int kt = 0; kt < 32; ++kt) {
        const int cur = kt & 1;
        if (kt + 1 < 32) XG_LOAD(kt + 1);
        h8 af[4], bf[4];
        #pragma unroll
        for (int mf = 0; mf < 4; ++mf) af[mf] = *(const h8*)&As[cur][wr + mf * 16 + lr][lg * 8];
        #pragma unroll
        for (int nf = 0; nf < 4; ++nf) bf[nf] = *(const h8*)&Bs[cur][wc + nf * 16 + lr][lg * 8];
        #pragma unroll
        for (int mf = 0; mf < 4; ++mf)
            #pragma unroll
            for (int nf = 0; nf < 4; ++nf)
                acc[mf][nf] = __builtin_amdgcn_mfma_f32_16x16x32_f16(af[mf], bf[nf], acc[mf][nf], 0, 0, 0);
        if (kt + 1 < 32) XG_WRITE((kt + 1) & 1);
        __syncthreads();
    }
    // epilogue: C row = m0+wr+mf*16+lg*4+r, col = n0+wc+nf*16+lr.
    // Consumer lane in the 8-wave packet = ((row&15)>>2)<<4 | (col&15) = this lane.
    #pragma unroll
    for (int nf = 0; nf < 4; ++nf) {
        const int col  = n0 + wc + nf * 16 + lr;
        const float bv = bias[col];
        const int gate = col >> 8;
        const int w8   = (col >> 5) & 7;
        const int jt   = (col >> 4) & 1;
        #pragma unroll
        for (int mf = 0; mf < 4; ++mf) {
            const int rowb = m0 + wr + mf * 16 + lg * 4;
            const int tt = rowb >> 8;
            const int gb = (rowb >> 4) & 15;
            h4 pk;
            #pragma unroll
            for (int r = 0; r < 4; ++r) pk[r] = (_Float16)(acc[mf][nf][r] + bv);
            *(h4*)&xg2[((((size_t)tt * 16 + gb) * 8 + w8) * 64 + l) * 32 + gate * 8 + jt * 4] = pk;
        }
    }
}

// ---------------------------------------------------------------- recurrence
// 16 blocks x 512 thr (8 waves, 2/SIMD). Wave w owns j in [w*32,(w+1)*32):
// 8 tiles ti = gate*2 + jt, 8 kb each -> 64 frags.
//   VGPR 24 : kb 0,1,2 all ti
//   LDS  17 : kb 3 -> ti, kb 4 -> 8+ti, kb 5/ti==0 -> 16   (per-wave region)
//   STREAM 23: kb5 ti 1..7, kb6 all, kb7 all (re-read from L2 each step)
__global__ __launch_bounds__(512, 2) void k_lstm_8w(
    const _Float16* __restrict__ xg2, const _Float16* __restrict__ Wp,
    _Float16* __restrict__ h_all)
{
    __shared__ _Float16 wlds[8 * 17 * 512];   // 139,264 B
    __shared__ _Float16 h_sh[2][16][264];     //  16,896 B  (total 156,160)
    const int tid = threadIdx.x;
    const int w  = tid >> 6;       // 0..7
    const int l  = tid & 63;
    const int lr = l & 15;
    const int lg = l >> 4;
    const int g  = blockIdx.x;
    const int b0 = g * 16;

    auto fgid = [&](int ti, int kb) {   // ti = gate*2+jt -> gt = gate*16 + w*2 + jt
        return (((ti >> 1) * 16 + w * 2 + (ti & 1)) * 8 + kb);
    };
    auto ldfrag = [&](int ti, int kb) {
        return *(const h8*)&Wp[((size_t)fgid(ti, kb) * 64 + l) * 8];
    };

    // ---- 24 VGPR-resident frags (kb 0..2)
    h8 wvg[24];
    #pragma unroll
    for (int kb = 0; kb < 3; ++kb)
        #pragma unroll
        for (int ti = 0; ti < 8; ++ti)
            wvg[kb * 8 + ti] = ldfrag(ti, kb);

    // ---- 17 LDS frags per wave
    #pragma unroll
    for (int ti = 0; ti < 8; ++ti)
        *(h8*)&wlds[((w * 17 + ti) * 64 + l) * 8] = ldfrag(ti, 3);
    #pragma unroll
    for (int ti = 0; ti < 8; ++ti)
        *(h8*)&wlds[((w * 17 + 8 + ti) * 64 + l) * 8] = ldfrag(ti, 4);
    *(h8*)&wlds[((w * 17 + 16) * 64 + l) * 8] = ldfrag(0, 5);

    // zero h_sh
    {
        _Float16* p = &h_sh[0][0][0];
        for (int i = tid; i < 2 * 16 * 264; i += 512) p[i] = (_Float16)0.f;
    }
    __syncthreads();

    float c[8];
    #pragma unroll
    for (int i = 0; i < 8; ++i) c[i] = 0.f;

    for (int t = 0; t < 256; ++t) {
        const int cur = t & 1;
        const int nxt = cur ^ 1;

        // xg packet: 64 B/lane, fully coalesced (4 x h8)
        const size_t E = ((((size_t)t * 16 + g) * 8 + w) * 64 + l) * 32;
        h8 xq[4];
        #pragma unroll
        for (int q = 0; q < 4; ++q) xq[q] = *(const h8*)&xg2[E + q * 8];

        // 23 streamed frags, issued at step start (first use at kb5 -> slack);
        // soff anti-hoist keeps them re-read from L2 instead of hoisted.
        unsigned soff = 0;
        asm volatile("" : "+v"(soff));
        h8 sv[23];
        #pragma unroll
        for (int ti = 1; ti < 8; ++ti)
            sv[ti - 1] = *(const h8*)&Wp[((size_t)fgid(ti, 5) * 64 + l) * 8 + soff];
        #pragma unroll
        for (int ti = 0; ti < 8; ++ti)
            sv[7 + ti] = *(const h8*)&Wp[((size_t)fgid(ti, 6) * 64 + l) * 8 + soff];
        #pragma unroll
        for (int ti = 0; ti < 8; ++ti)
            sv[15 + ti] = *(const h8*)&Wp[((size_t)fgid(ti, 7) * 64 + l) * 8 + soff];

        // acc init = xg (MFMA C-operand accumulates the matmul on top)
        f32x4 acc[8];
        #pragma unroll
        for (int ti = 0; ti < 8; ++ti) {
            #pragma unroll
            for (int r = 0; r < 4; ++r)
                acc[ti][r] = (float)xq[ti >> 1][(ti & 1) * 4 + r];
        }

        #pragma unroll
        for (int kb = 0; kb < 8; ++kb) {
            const h8 av = *(const h8*)&h_sh[cur][lr][kb * 32 + lg * 8];
            #pragma unroll
            for (int ti = 0; ti < 8; ++ti) {
                h8 b;
                if (kb < 3)                  b = wvg[kb * 8 + ti];
                else if (kb == 3)            b = *(const h8*)&wlds[((w * 17 + ti) * 64 + l) * 8];
                else if (kb == 4)            b = *(const h8*)&wlds[((w * 17 + 8 + ti) * 64 + l) * 8];
                else if (kb == 5 && ti == 0) b = *(const h8*)&wlds[((w * 17 + 16) * 64 + l) * 8];
                else if (kb == 5)            b = sv[ti - 1];
                else if (kb == 6)            b = sv[7 + ti];
                else                         b = sv[15 + ti];
                acc[ti] = __builtin_amdgcn_mfma_f32_16x16x32_f16(av, b, acc[ti], 0, 0, 0);
            }
        }

        // activations: lane holds z for b = lg*4+r, j = w*32+jt*16+lr, all gates
        #pragma unroll
        for (int jt = 0; jt < 2; ++jt) {
            #pragma unroll
            for (int r = 0; r < 4; ++r) {
                const float ig = fast_sigmoid(acc[0 * 2 + jt][r]);
                const float fg = fast_sigmoid(acc[1 * 2 + jt][r]);
                const float gg = fast_tanh(acc[2 * 2 + jt][r]);
                const float og = fast_sigmoid(acc[3 * 2 + jt][r]);
                const int ci = jt * 4 + r;
                c[ci] = fg * c[ci] + ig * gg;
                const float hv = og * fast_tanh(c[ci]);
                const _Float16 h16 = (_Float16)hv;
                h_sh[nxt][lg * 4 + r][w * 32 + jt * 16 + lr] = h16;
                h_all[((size_t)t * 256 + b0 + lg * 4 + r) * 256 + w * 32 + jt * 16 + lr] = h16;
            }
        }
        __syncthreads();
    }
}

// ---------------------------------------------------------------- FC1+FC2
template <typename HT>
__global__ __launch_bounds__(256) void k_fc(
    const HT* __restrict__ h_all, const float* __restrict__ W1,
    const float* __restrict__ b1, const float* __restrict__ W2,
    const float* __restrict__ b2, float* __restrict__ out)
{
    __shared__ __align__(16) float smem[12288];
    float* hsT = smem;
    float* w1T = smem + 4096;
    const int tid = threadIdx.x;
    const int m0 = blockIdx.x * 64;
    const int tx = tid & 15;
    const int ty = tid >> 4;
    const int r0 = ty * 4;
    const int fA = tx * 4;
    const int fB = 64 + tx * 4;
    float acc[4][8] = {};
    for (int kc = 0; kc < 4; ++kc) {
        const int k0 = kc * 64;
        __syncthreads();
        #pragma unroll
        for (int i = 0; i < 4; ++i) {
            const int fid = tid + i * 256;
            const int rr = fid >> 4;
            const int qq = fid & 15;
            const HT* p = &h_all[(size_t)(m0 + rr) * 256 + k0 + qq * 4];
            f4 v;
            if constexpr (std::is_same<HT, float>::value) {
                v = *(const f4*)p;
            } else {
                v[0] = ldf(p); v[1] = ldf(p + 1); v[2] = ldf(p + 2); v[3] = ldf(p + 3);
            }
            #pragma unroll
            for (int cc = 0; cc < 4; ++cc)
                hsT[(qq * 4 + cc) * 64 + rr] = fmaxf(v[cc], 0.f);
        }
        #pragma unroll
        for (int i = 0; i < 8; ++i) {
            const int fid = tid + i * 256;
            const int ff = fid >> 4;
            const int qq = fid & 15;
            const f4 v = *(const f4*)&W1[(size_t)ff * 256 + k0 + qq * 4];
            #pragma unroll
            for (int cc = 0; cc < 4; ++cc)
                w1T[(qq * 4 + cc) * 128 + ff] = v[cc];
        }
        __syncthreads();
        #pragma unroll 4
        for (int kk = 0; kk < 64; ++kk) {
            const f4 aa = *(const f4*)&hsT[kk * 64 + r0];
            const f4 ba = *(const f4*)&w1T[kk * 128 + fA];
            const f4 bb = *(const f4*)&w1T[kk * 128 + fB];
            #pragma unroll
            for (int i = 0; i < 4; ++i) {
                #pragma unroll
                for (int j = 0; j < 4; ++j) {
                    acc[i][j]     = fmaf(aa[i], ba[j], acc[i][j]);
                    acc[i][j + 4] = fmaf(aa[i], bb[j], acc[i][j + 4]);
                }
            }
        }
    }
    __syncthreads();
    float* fc1s = smem;
    #pragma unroll
    for (int j = 0; j < 4; ++j) {
        const float bbA = b1[fA + j];
        const float bbB = b1[fB + j];
        #pragma unroll
        for (int i = 0; i < 4; ++i) {
            fc1s[(r0 + i) * 132 + fA + j] = fmaxf(acc[i][j] + bbA, 0.f);
            fc1s[(r0 + i) * 132 + fB + j] = fmaxf(acc[i][j + 4] + bbB, 0.f);
        }
    }
    __syncthreads();
    const int r  = tid >> 2;
    const int c0 = (tid & 3) * 2;
    float o0 = b2[c0], o1 = b2[c0 + 1];
    #pragma unroll
    for (int fq = 0; fq < 32; ++fq) {
        const f4 p  = *(const f4*)&fc1s[r * 132 + fq * 4];
        const f4 wa = *(const f4*)&W2[(size_t)c0 * 128 + fq * 4];
        const f4 wb = *(const f4*)&W2[(size_t)(c0 + 1) * 128 + fq * 4];
        o0 += p[0] * wa[0] + p[1] * wa[1] + p[2] * wa[2] + p[3] * wa[3];
        o1 += p[0] * wb[0] + p[1] * wb[1] + p[2] * wb[2] + p[3] * wb[3];
    }
    out[(size_t)(m0 + r) * 8 + c0]     = o0;
    out[(size_t)(m0 + r) * 8 + c0 + 1] = o1;
}

// ---------------------------------------------------------------- launch
extern "C" void kernel_launch(void* const* d_in, const int* in_sizes, int n_in,
                              void* d_out, int out_size, void* d_ws, size_t ws_size,
                              hipStream_t stream)
{
    const float* x    = (const float*)d_in[0];
    const float* W_ih = (const float*)d_in[1];
    const float* W_hh = (const float*)d_in[2];
    const float* b_ih = (const float*)d_in[3];
    const float* b_hh = (const float*)d_in[4];
    const float* W1   = (const float*)d_in[5];
    const float* b1   = (const float*)d_in[6];
    const float* W2   = (const float*)d_in[7];
    const float* b2   = (const float*)d_in[8];
    float* out = (float*)d_out;
    char* ws = (char*)d_ws;

    // workspace layout (168,300,544 B)
    _Float16* xg2   = (_Float16*)ws;                          // 134,217,728 B
    _Float16* h_all = (_Float16*)(ws + 134217728);            //  33,554,432 B
    _Float16* Wp    = (_Float16*)(ws + 167772160);            //     524,288 B
    float*    bias  = (float*)   (ws + 168296448);            //       4,096 B

    k_bias<<<4, 256, 0, stream>>>(b_ih, b_hh, bias);
    k_pack<<<128, 256, 0, stream>>>(W_hh, Wp);
    k_xg_mfma<<<dim3(8, 512), 256, 0, stream>>>(x, W_ih, bias, xg2);
    k_lstm_8w<<<16, 512, 0, stream>>>(xg2, Wp, h_all);
    k_fc<_Float16><<<1024, 256, 0, stream>>>(h_all, W1, b1, W2, b2, out);
}